// Round 7
// baseline (330.308 us; speedup 1.0000x reference)
//
#include <hip/hip_runtime.h>
#include <hip/hip_bf16.h>

// Effi_MVS: B=1, V=5, C=32, D=48, H=128, W=160, RATIO=8. fp32 in, fp32 out.
// Round 7: kill the gathers. The problem's projection matrices give
// proj = src @ inv(ref) with rot == I and trans == (f*2v, 0, 0), so
// gy == y exactly and gx == x + f*tx/d: the warp is a uniform x-shift with
// wave-uniform fractional weight. k_setup detects this numerically and
// builds a per-(v,d) {floor(off), frac(off)} table; k_warpvar then does one
// COALESCED f32x2 read per (c,v) instead of scattered gathers (r6 lesson:
// gather cost = distinct cache lines per wave, halving instr count was
// neutral). General r6 gather path kept as uniform-branch fallback.

#define NV 5
#define NC 32
#define ND 48
#define NH 128
#define NW 160
#define HW (NH * NW)
#define DHW (ND * HW)

typedef __attribute__((ext_vector_type(2))) float f32x2;
typedef __attribute__((ext_vector_type(2), aligned(4))) float f32x2u;

// ws layout (bytes)
#define OFF_M      0          // float M[4][12]
#define OFF_WF     256        // float wf[32][28] (ends 3840)
#define OFF_TBL    4096       // float tbl[4][48][2] {s,w} (ends 5632) — overlaid
#define OFF_FLAG   5632       // int flag (1=shift path)      by depthf later
#define OFF_DEPTHF 4096       // float depthf[20480] (written at softmax, after
                              //   tbl+flag are dead) (ends 86016)
#define OFF_PRE    86016      // float pre[DHW] (ends 4018176)
#define OFF_WV     4018176    // bf16 WV[27][DHW] (ends 57102336, proven fits)

// ---------------------------------------------------------------- K1: setup
__global__ void k_setup(const float* __restrict__ proj,
                        const float* __restrict__ wreg,
                        const float* __restrict__ depthv,
                        float* __restrict__ M, float* __restrict__ wf,
                        float* __restrict__ tbl, int* __restrict__ flag) {
  if (threadIdx.x != 0) return;
  double P[NV][2][4][4];
  for (int v = 0; v < NV; ++v)
    for (int m = 0; m < 2; ++m)
      for (int i = 0; i < 4; ++i)
        for (int j = 0; j < 4; ++j)
          P[v][m][i][j] = (double)proj[((v * 2 + m) * 4 + i) * 4 + j];
  double C[NV][4][4];
  for (int v = 0; v < NV; ++v) {
    for (int i = 0; i < 4; ++i)
      for (int j = 0; j < 4; ++j) C[v][i][j] = P[v][0][i][j];
    for (int i = 0; i < 3; ++i)
      for (int j = 0; j < 4; ++j) {
        double s = 0.0;
        for (int k = 0; k < 3; ++k) s += P[v][1][i][k] * P[v][0][k][j];
        C[v][i][j] = s;
      }
  }
  double a[4][8];
  for (int i = 0; i < 4; ++i)
    for (int j = 0; j < 4; ++j) { a[i][j] = C[0][i][j]; a[i][j + 4] = (i == j) ? 1.0 : 0.0; }
  for (int col = 0; col < 4; ++col) {
    int piv = col; double best = fabs(a[col][col]);
    for (int r = col + 1; r < 4; ++r) { double v = fabs(a[r][col]); if (v > best) { best = v; piv = r; } }
    if (piv != col)
      for (int j = 0; j < 8; ++j) { double t = a[col][j]; a[col][j] = a[piv][j]; a[piv][j] = t; }
    double pv = a[col][col];
    for (int j = 0; j < 8; ++j) a[col][j] /= pv;
    for (int r = 0; r < 4; ++r) if (r != col) {
      double f = a[r][col];
      for (int j = 0; j < 8; ++j) a[r][j] -= f * a[col][j];
    }
  }
  double inv[4][4];
  for (int i = 0; i < 4; ++i)
    for (int j = 0; j < 4; ++j) inv[i][j] = a[i][j + 4];

  bool shiftOK = true;
  double Tx[4];
  for (int v = 1; v < NV; ++v) {
    double rm[12];  // rot 9 + trans 3
    float* m = M + (v - 1) * 12;
    for (int i = 0; i < 3; ++i) {
      double r[4] = {0, 0, 0, 0};
      for (int k = 0; k < 4; ++k) {
        double cv = C[v][i][k];
        for (int j = 0; j < 4; ++j) r[j] += cv * inv[k][j];
      }
      rm[i * 3 + 0] = r[0]; rm[i * 3 + 1] = r[1]; rm[i * 3 + 2] = r[2];
      rm[9 + i] = r[3];
      m[i * 3 + 0] = (float)r[0]; m[i * 3 + 1] = (float)r[1]; m[i * 3 + 2] = (float)r[2];
      m[9 + i] = (float)r[3];
    }
    // structure check: rot == I, trans y/z == 0
    for (int i = 0; i < 3; ++i)
      for (int j = 0; j < 3; ++j) {
        double want = (i == j) ? 1.0 : 0.0;
        if (fabs(rm[i * 3 + j] - want) > 1e-4) shiftOK = false;
      }
    if (fabs(rm[10]) > 1e-4 || fabs(rm[11]) > 1e-4) shiftOK = false;
    Tx[v - 1] = rm[9];
  }
  *flag = shiftOK ? 1 : 0;
  if (shiftOK) {
    for (int v = 0; v < 4; ++v)
      for (int d = 0; d < ND; ++d) {
        double off = Tx[v] / (double)depthv[d];
        double s = floor(off);
        tbl[(v * ND + d) * 2 + 0] = (float)s;
        tbl[(v * ND + d) * 2 + 1] = (float)(off - s);
      }
  }
  for (int c = 0; c < NC; ++c) {
    for (int t = 0; t < 27; ++t) wf[c * 28 + t] = wreg[c * 27 + t];
    wf[c * 28 + 27] = 0.f;
  }
}

// ----------------------- K2: warp + variance + channel-contract (block=256)
__device__ __forceinline__ void warpvar_store(
    const f32x2* wv2, __hip_bfloat16* __restrict__ WV, int idx) {
#pragma unroll
  for (int u = 0; u < 14; ++u) {
    int t0 = 2 * u;
    WV[(size_t)t0 * DHW + idx] = __float2bfloat16(wv2[u].x);
    if (t0 + 1 < 27) WV[(size_t)(t0 + 1) * DHW + idx] = __float2bfloat16(wv2[u].y);
  }
}

__global__ __launch_bounds__(256) void k_warpvar(
    const float* __restrict__ feat,    // [5][32][128][160] channel-first
    const float* __restrict__ depthv,  // [48]
    const float* __restrict__ M,       // [4][12]
    const float* __restrict__ wf,      // [32][28]
    const float* __restrict__ tbl,     // [4][48][2]
    const int* __restrict__ flag,
    __hip_bfloat16* __restrict__ WV)   // [27][DHW]
{
  int idx = blockIdx.x * 256 + threadIdx.x;
  int x = idx % NW;
  int t1 = idx / NW;
  int y = t1 % NH;
  int d = t1 / NH;
  int pix = y * NW + x;

  f32x2 wv2[14];
#pragma unroll
  for (int u = 0; u < 14; ++u) wv2[u] = (f32x2){0.f, 0.f};

  if (*flag) {
    // ---------------- specialized: uniform x-shift warp ----------------
    int   xb[4];
    float A[4], B[4];
#pragma unroll
    for (int v = 0; v < 4; ++v) {
      float sf = tbl[(v * ND + d) * 2 + 0];   // block-uniform scalar loads
      float w  = tbl[(v * ND + d) * 2 + 1];
      int sx = (int)sf;
      int x0 = x + sx;
      float wl = (x0 >= 0 && x0 <= NW - 1) ? (1.f - w) : 0.f;
      float wr = (x0 >= -1 && x0 <= NW - 2) ? w : 0.f;
      bool leftIsP1 = (x0 >= NW - 1);   // p0 sits at pair slot .y
      bool rightIsP0 = (x0 < 0);        // p1 sits at pair slot .x
      A[v] = (leftIsP1 ? 0.f : wl) + (rightIsP0 ? wr : 0.f);
      B[v] = (leftIsP1 ? wl : 0.f) + (rightIsP0 ? 0.f : wr);
      int xc = min(max(x0, 0), NW - 2);
      xb[v] = y * NW + xc;
    }
#pragma unroll
    for (int c = 0; c < NC; ++c) {
      float f0 = feat[c * HW + pix];           // coalesced
      float vs = f0, vq = f0 * f0;
#pragma unroll
      for (int v = 0; v < 4; ++v) {
        const float* fv = feat + ((size_t)((v + 1) * NC + c)) * HW;
        f32x2u q = *(const f32x2u*)(fv + xb[v]);   // coalesced pair
        float val = A[v] * q.x + B[v] * q.y;
        vs += val;
        vq += val * val;
      }
      float var = vq * 0.2f - (vs * 0.2f) * (vs * 0.2f);
      const f32x2* wrow = (const f32x2*)(wf + c * 28);
      f32x2 vv; vv.x = var; vv.y = var;
#pragma unroll
      for (int u = 0; u < 14; ++u) wv2[u] += wrow[u] * vv;
    }
  } else {
    // ---------------- general homography fallback (r6 path) ----------------
    float xf = (float)x, yf = (float)y;
    float df = depthv[d];
    int   r0i[4], r1i[4];
    float W00[4], W10[4], W01[4], W11[4];
#pragma unroll
    for (int v = 0; v < 4; ++v) {
      const float* m = M + v * 12;
      float rx = m[0] * xf + m[1] * yf + m[2];
      float ry = m[3] * xf + m[4] * yf + m[5];
      float rz = m[6] * xf + m[7] * yf + m[8];
      float px = rx * df + m[9];
      float py = ry * df + m[10];
      float pz = rz * df + m[11];
      float gx = px / pz;
      float gy = py / pz;
      float x0f = floorf(gx), y0f = floorf(gy);
      float wx = gx - x0f, wy = gy - y0f;
      float vx0 = (x0f >= 0.f && x0f <= (float)(NW - 1)) ? 1.f : 0.f;
      float vx1 = (x0f + 1.f >= 0.f && x0f + 1.f <= (float)(NW - 1)) ? 1.f : 0.f;
      float vy0 = (y0f >= 0.f && y0f <= (float)(NH - 1)) ? 1.f : 0.f;
      float vy1 = (y0f + 1.f >= 0.f && y0f + 1.f <= (float)(NH - 1)) ? 1.f : 0.f;
      float xbf = fminf(fmaxf(x0f, 0.f), (float)(NW - 2));
      int xbv = (int)xbf;
      float wl = (1.f - wx) * vx0;
      float wr = wx * vx1;
      bool leftIsP1 = (x0f > (float)(NW - 2));
      bool rightIsP0 = (x0f < 0.f);
      float ax = (leftIsP1 ? 0.f : wl) + (rightIsP0 ? wr : 0.f);
      float bx = (leftIsP1 ? wl : 0.f) + (rightIsP0 ? 0.f : wr);
      float yb0f = fminf(fmaxf(y0f, 0.f), (float)(NH - 1));
      float yb1f = fminf(fmaxf(y0f + 1.f, 0.f), (float)(NH - 1));
      r0i[v] = (int)yb0f * NW + xbv;
      r1i[v] = (int)yb1f * NW + xbv;
      float wy0 = (1.f - wy) * vy0, wy1 = wy * vy1;
      W00[v] = ax * wy0; W10[v] = bx * wy0;
      W01[v] = ax * wy1; W11[v] = bx * wy1;
    }
#pragma unroll
    for (int c = 0; c < NC; ++c) {
      float f0 = feat[c * HW + pix];
      float vs = f0, vq = f0 * f0;
#pragma unroll
      for (int v = 0; v < 4; ++v) {
        const float* fv = feat + ((size_t)((v + 1) * NC + c)) * HW;
        f32x2u q0 = *(const f32x2u*)(fv + r0i[v]);
        f32x2u q1 = *(const f32x2u*)(fv + r1i[v]);
        float val = W00[v] * q0.x + W10[v] * q0.y
                  + W01[v] * q1.x + W11[v] * q1.y;
        vs += val;
        vq += val * val;
      }
      float var = vq * 0.2f - (vs * 0.2f) * (vs * 0.2f);
      const f32x2* wrow = (const f32x2*)(wf + c * 28);
      f32x2 vv; vv.x = var; vv.y = var;
#pragma unroll
      for (int u = 0; u < 14; ++u) wv2[u] += wrow[u] * vv;
    }
  }
  warpvar_store(wv2, WV, idx);
}

// ------------------------------------------------- K3a: 27-tap gather (conv)
__global__ __launch_bounds__(256) void k_conv(const __hip_bfloat16* __restrict__ WV,
                                              float* __restrict__ pre) {
  int idx = blockIdx.x * 256 + threadIdx.x;
  int x = idx % NW;
  int t1 = idx / NW;
  int y = t1 % NH;
  int d = t1 / NH;
  float acc = 0.f;
#pragma unroll
  for (int dd = 0; dd < 3; ++dd) {
    int dp = d + dd - 1;
    bool dok = (dp >= 0) && (dp < ND);
    int dpc = min(max(dp, 0), ND - 1);
#pragma unroll
    for (int i = 0; i < 3; ++i) {
      int yp = y + i - 1;
      bool yok = (yp >= 0) && (yp < NH);
      int ypc = min(max(yp, 0), NH - 1);
#pragma unroll
      for (int j = 0; j < 3; ++j) {
        int xp = x + j - 1;
        bool xok = (xp >= 0) && (xp < NW);
        int xpc = min(max(xp, 0), NW - 1);
        int t = dd * 9 + i * 3 + j;
        float v = __bfloat162float(WV[(size_t)t * DHW + dpc * HW + ypc * NW + xpc]);
        acc += (dok && yok && xok) ? v : 0.f;
      }
    }
  }
  pre[idx] = acc;
}

// ---------------------------------------- K3b: softmax over D + depth + conf
__global__ __launch_bounds__(256) void k_softmax(const float* __restrict__ pre,
                                                 const float* __restrict__ depthv,
                                                 float* __restrict__ depthf,
                                                 float* __restrict__ out_depth,
                                                 float* __restrict__ out_conf) {
  int p = blockIdx.x * 256 + threadIdx.x;
  float pr[ND];
  float m = -1e30f;
#pragma unroll
  for (int d = 0; d < ND; ++d) { pr[d] = pre[d * HW + p]; m = fmaxf(m, pr[d]); }
  float s = 0.f;
#pragma unroll
  for (int d = 0; d < ND; ++d) { pr[d] = expf(pr[d] - m); s += pr[d]; }
  float inv = 1.f / s;
  float dep = 0.f, ti = 0.f;
#pragma unroll
  for (int d = 0; d < ND; ++d) {
    float prob = pr[d] * inv;
    pr[d] = prob;
    dep += prob * depthv[d];
    ti += prob * (float)d;
  }
  int di = (int)ti;
  di = di < 0 ? 0 : (di > ND - 1 ? ND - 1 : di);
  float conf = 0.f;
#pragma unroll
  for (int d = 0; d < ND; ++d)
    conf += (d >= di - 1 && d <= di + 2) ? pr[d] : 0.f;
  depthf[p] = dep;
  out_depth[p] = dep;
  out_conf[p] = conf;
}

// ------------------------------- K4: convex upsample, block=(y,dy), 640 thr
__global__ __launch_bounds__(640) void k_upsample(const float* __restrict__ mask,
                                                  const float* __restrict__ depthf,
                                                  float* __restrict__ out) {
  __shared__ float row[NW * 8];
  int y = blockIdx.x >> 3;
  int dy = blockIdx.x & 7;
#pragma unroll
  for (int rep = 0; rep < 2; ++rep) {
    int lin = rep * 640 + threadIdx.x;
    int dx = lin / NW;
    int x = lin % NW;
    float mv[9];
    float mmax = -1e30f;
#pragma unroll
    for (int k = 0; k < 9; ++k) {
      mv[k] = mask[(size_t)(k * 64 + dy * 8 + dx) * HW + y * NW + x];
      mmax = fmaxf(mmax, mv[k]);
    }
    float s = 0.f;
#pragma unroll
    for (int k = 0; k < 9; ++k) { mv[k] = expf(mv[k] - mmax); s += mv[k]; }
    float acc = 0.f;
#pragma unroll
    for (int k = 0; k < 9; ++k) {
      int ky = y + k / 3 - 1;
      int kx = x + k % 3 - 1;
      bool ok = (ky >= 0) && (ky < NH) && (kx >= 0) && (kx < NW);
      int kyc = min(max(ky, 0), NH - 1);
      int kxc = min(max(kx, 0), NW - 1);
      float dv = depthf[kyc * NW + kxc];
      acc += mv[k] * (ok ? dv : 0.f);
    }
    row[x * 8 + dx] = acc / s;
  }
  __syncthreads();
  float* orow = out + (size_t)(y * 8 + dy) * (NW * 8);
#pragma unroll
  for (int rep = 0; rep < 2; ++rep) {
    int j = rep * 640 + threadIdx.x;
    orow[j] = row[j];
  }
}

// ---------------------------------------------------------------- launcher
extern "C" void kernel_launch(void* const* d_in, const int* in_sizes, int n_in,
                              void* d_out, int out_size, void* d_ws, size_t ws_size,
                              hipStream_t stream) {
  const float* feat   = (const float*)d_in[0];
  const float* proj   = (const float*)d_in[1];
  const float* depthv = (const float*)d_in[2];
  const float* mask   = (const float*)d_in[3];
  const float* wreg   = (const float*)d_in[4];

  char* ws = (char*)d_ws;
  float* M       = (float*)(ws + OFF_M);
  float* wf      = (float*)(ws + OFF_WF);
  float* tbl     = (float*)(ws + OFF_TBL);
  int*   flag    = (int*)(ws + OFF_FLAG);
  float* depthf  = (float*)(ws + OFF_DEPTHF);
  float* pre     = (float*)(ws + OFF_PRE);
  __hip_bfloat16* WV = (__hip_bfloat16*)(ws + OFF_WV);

  float* out = (float*)d_out;
  float* out_depth = out + (NH * 8) * (NW * 8);
  float* out_conf  = out_depth + HW;

  k_setup<<<1, 64, 0, stream>>>(proj, wreg, depthv, M, wf, tbl, flag);
  k_warpvar<<<DHW / 256, 256, 0, stream>>>(feat, depthv, M, wf, tbl, flag, WV);
  k_conv<<<DHW / 256, 256, 0, stream>>>(WV, pre);
  k_softmax<<<HW / 256, 256, 0, stream>>>(pre, depthv, depthf, out_depth, out_conf);
  k_upsample<<<NH * 8, 640, 0, stream>>>(mask, depthf, out);
}